// Round 2
// baseline (121.278 us; speedup 1.0000x reference)
//
#include <hip/hip_runtime.h>
#include <math.h>

#define N 1024
#define B_ 8
#define T_ 256
#define NREP 4
#define CHUNKS 64

// ws layout (float index)
#define OFF_SF      0        // 1024 x float2 (element shift factor)
#define OFF_TA      2048     // 16(k1) x 64(lane) x float2 : W_1024^{lane*k1}
#define OFF_TB      6144     // 16(k2) x 4(n3) x float2    : W_64^{n3*k2}
#define OFF_ROWSUM  6272     // 8 x 1024
#define ZERO_START  14464
#define OFF_COLSUMM 14464    // 1024
#define OFF_SUMM2   15488
#define OFF_MAXM    15489
#define OFF_SUMMT   15496    // 8
#define OFF_SUMTT   15504    // 8
#define OFF_COLT    15520    // 8 batches x NREP x 1024
#define WS_END      (OFF_COLT + B_ * NREP * N)

__device__ __forceinline__ float wave_sum(float v) {
    #pragma unroll
    for (int o = 32; o > 0; o >>= 1) v += __shfl_down(v, o, 64);
    return v;
}
__device__ __forceinline__ float wave_max(float v) {
    #pragma unroll
    for (int o = 32; o > 0; o >>= 1) v = fmaxf(v, __shfl_down(v, o, 64));
    return v;
}

__device__ __forceinline__ void cmul(float& xr, float& xi, float wr, float wi) {
    float r = xr * wr - xi * wi;
    float i = xr * wi + xi * wr;
    xr = r; xi = i;
}

// 4-pt DFT (W4 = -i), outputs in natural order in place
__device__ __forceinline__ void dft4(float& r0, float& i0, float& r1, float& i1,
                                     float& r2, float& i2, float& r3, float& i3) {
    float e0r = r0 + r2, e0i = i0 + i2;
    float e1r = r0 - r2, e1i = i0 - i2;
    float e2r = r1 + r3, e2i = i1 + i3;
    float e3r = r1 - r3, e3i = i1 - i3;
    r0 = e0r + e2r; i0 = e0i + e2i;
    r2 = e0r - e2r; i2 = e0i - e2i;
    r1 = e1r + e3i; i1 = e1i - e3r;   // e1 - i*e3
    r3 = e1r - e3i; i3 = e1i + e3r;   // e1 + i*e3
}

// 16-pt DFT over register index n (natural order in).
// Output: slot r = 4c+d holds S[k = c+4d]  (digit-swapped order).
__device__ __forceinline__ void dft16(float xr[16], float xi[16]) {
    #pragma unroll
    for (int b = 0; b < 4; ++b)
        dft4(xr[b], xi[b], xr[4 + b], xi[4 + b], xr[8 + b], xi[8 + b], xr[12 + b], xi[12 + b]);
    const float C1 = 0.9238795325112867f, S1 = 0.3826834323650898f;
    const float C2 = 0.7071067811865476f;
    // slot[4c+b] *= W16^{b*c}
    cmul(xr[5],  xi[5],   C1, -S1);   // bc=1
    cmul(xr[6],  xi[6],   C2, -C2);   // bc=2
    cmul(xr[7],  xi[7],   S1, -C1);   // bc=3
    cmul(xr[9],  xi[9],   C2, -C2);   // bc=2
    { float t = xr[10]; xr[10] = xi[10]; xi[10] = -t; }  // bc=4 : * (0,-1)
    cmul(xr[11], xi[11], -C2, -C2);   // bc=6
    cmul(xr[13], xi[13],  S1, -C1);   // bc=3
    cmul(xr[14], xi[14], -C2, -C2);   // bc=6
    cmul(xr[15], xi[15], -C1,  S1);   // bc=9
    #pragma unroll
    for (int c = 0; c < 4; ++c)
        dft4(xr[4 * c], xi[4 * c], xr[4 * c + 1], xi[4 * c + 1],
             xr[4 * c + 2], xi[4 * c + 2], xr[4 * c + 3], xi[4 * c + 3]);
}

// DPP quad-perm move (cross-lane within each 4-lane quad), VALU-only
template<int CTRL>
__device__ __forceinline__ float dppf(float x) {
    return __int_as_float(__builtin_amdgcn_update_dpp(
        0, __float_as_int(x), CTRL, 0xF, 0xF, true));
}
#define DPP_XOR1 0xB1   // quad_perm [1,0,3,2]
#define DPP_XOR2 0x4E   // quad_perm [2,3,0,1]

// tables + zero accumulators: 12 blocks x 256 threads
__global__ __launch_bounds__(T_) void k_prep(float* ws, float* out) {
    const int e = blockIdx.x * T_ + threadIdx.x;   // 0..3071
    if (e < 1024) {
        double ang = -2.0 * 337.927 * 1.5 * (double)(e - 512);
        double s, c;
        sincos(ang, &s, &c);
        ws[OFF_SF + 2 * e]     = (float)c;
        ws[OFF_SF + 2 * e + 1] = (float)s;
    } else if (e < 2048) {
        int e2 = e - 1024;
        int k1 = e2 >> 6, uu = e2 & 63;
        double ang = -2.0 * M_PI * (double)(uu * k1) / 1024.0;
        double s, c;
        sincos(ang, &s, &c);
        ws[OFF_TA + 2 * e2]     = (float)c;
        ws[OFF_TA + 2 * e2 + 1] = (float)s;
    } else if (e < 2112) {
        int e2 = e - 2048;
        int k2 = e2 >> 2, n3 = e2 & 3;
        double ang = -2.0 * M_PI * (double)(n3 * k2) / 64.0;
        double s, c;
        sincos(ang, &s, &c);
        ws[OFF_TB + 2 * e2]     = (float)c;
        ws[OFF_TB + 2 * e2 + 1] = (float)s;
    }
    for (int j = ZERO_START + e; j < WS_END; j += 12 * T_) ws[j] = 0.f;
    if (e == 0) out[0] = 0.f;
}

// grid (64, 9):
//   y < 8 : FFT blocks — batch y, chunk x covers rows 8x..8x+7 (one wave = 2 rows,
//           wave-private 1024-pt FFT: radix-16(reg) -> LDS transpose -> radix-16(reg)
//           -> radix-4 via DPP quad shuffles). chunk 63 wave 0 also does m=512.
//   y == 8: M-stats (64 blocks, 16 rows each)
__global__ __launch_bounds__(T_, 3) void k_row(const float* __restrict__ pred,
                                               const float* __restrict__ M,
                                               float* __restrict__ ws) {
    __shared__ float2 Y2[N];        // y interleaved
    __shared__ float2 Ysf2[N];      // y * shiftfactor
    __shared__ float2 TP[4][N];     // per-wave transpose buffers
    __shared__ float2 TB2[64];      // W_64^{n3*k2}
    __shared__ float red[2][4];
    const int t = threadIdx.x;
    const int cnk = blockIdx.x;
    const int b = blockIdx.y;
    const int wid = t >> 6, u = t & 63;

    if (b == B_) {
        // ---- M-stats slice ----
        const int r0 = cnk * 16;
        float cs0 = 0.f, cs1 = 0.f, cs2 = 0.f, cs3 = 0.f, sq = 0.f, mx = 0.f;
        for (int r = 0; r < 16; ++r) {
            const float* row = M + (size_t)(r0 + r) * N;
            float v0 = row[t], v1 = row[t + 256], v2 = row[t + 512], v3 = row[t + 768];
            cs0 += v0; cs1 += v1; cs2 += v2; cs3 += v3;
            sq += v0 * v0 + v1 * v1 + v2 * v2 + v3 * v3;
            mx = fmaxf(mx, fmaxf(fmaxf(v0, v1), fmaxf(v2, v3)));
        }
        atomicAdd(&ws[OFF_COLSUMM + t],       cs0);
        atomicAdd(&ws[OFF_COLSUMM + t + 256], cs1);
        atomicAdd(&ws[OFF_COLSUMM + t + 512], cs2);
        atomicAdd(&ws[OFF_COLSUMM + t + 768], cs3);
        sq = wave_sum(sq);
        mx = wave_max(mx);
        if (u == 0) { red[0][wid] = sq; red[1][wid] = mx; }
        __syncthreads();
        if (t == 0) {
            atomicAdd(&ws[OFF_SUMM2], red[0][0] + red[0][1] + red[0][2] + red[0][3]);
            float X = fmaxf(fmaxf(red[1][0], red[1][1]), fmaxf(red[1][2], red[1][3]));
            atomicMax((unsigned int*)ws + OFF_MAXM, __float_as_uint(X));
        }
        return;
    }

    // ---- staging: y, y*sf into LDS; tB into LDS; tA into registers ----
    {
        const float* pr = pred + (size_t)b * 2 * N;
        float4 re = *(const float4*)(pr + 4 * t);
        float4 im = *(const float4*)(pr + N + 4 * t);
        const float4* sfp = (const float4*)(ws + OFF_SF);
        float4 sA = sfp[2 * t], sB = sfp[2 * t + 1];
        int j0 = 4 * t;
        Y2[j0 + 0] = make_float2(re.x, im.x);
        Y2[j0 + 1] = make_float2(re.y, im.y);
        Y2[j0 + 2] = make_float2(re.z, im.z);
        Y2[j0 + 3] = make_float2(re.w, im.w);
        Ysf2[j0 + 0] = make_float2(re.x * sA.x - im.x * sA.y, re.x * sA.y + im.x * sA.x);
        Ysf2[j0 + 1] = make_float2(re.y * sA.z - im.y * sA.w, re.y * sA.w + im.y * sA.z);
        Ysf2[j0 + 2] = make_float2(re.z * sB.x - im.z * sB.y, re.z * sB.y + im.z * sB.x);
        Ysf2[j0 + 3] = make_float2(re.w * sB.z - im.w * sB.w, re.w * sB.w + im.w * sB.z);
        if (t < 64) TB2[t] = ((const float2*)(ws + OFF_TB))[t];
    }
    float tar[16], tai[16];
    {
        const float2* taT = (const float2*)(ws + OFF_TA);
        #pragma unroll
        for (int r = 1; r < 16; ++r) {
            int k1 = ((r & 3) << 2) | (r >> 2);
            float2 wv = taT[(k1 << 6) + u];
            tar[r] = wv.x; tai[r] = wv.y;
        }
    }
    __syncthreads();   // the only block barrier in the FFT path

    const int k1u = u >> 2;
    const int n3 = u & 3;
    const int k3 = ((u & 1) << 1) | ((u >> 1) & 1);   // bitrev2(n3)
    const int clane = (k1u | (k3 << 8)) ^ 512;        // output column base (incl. fftshift)
    const bool hi2 = (u & 2) != 0;
    const bool odd = (u & 1) != 0;
    float2* tp = TP[wid];

    float colr[16];
    #pragma unroll
    for (int r = 0; r < 16; ++r) colr[r] = 0.f;
    float mtl = 0.f, ttl = 0.f;

    const int base = cnk * 8 + wid * 2;
    const int nrow = (cnk == CHUNKS - 1 && wid == 0) ? 3 : 2;

    for (int rr = 0; rr < nrow; ++rr) {
        const int m = (rr < 2) ? (base + rr) : 512;
        const int mm = (N - m) & (N - 1);
        const float w = (mm == m) ? 1.f : 2.f;

        float xr[16], xi[16];
        // phase A: product + radix-16 over n1 (lane-local elements 64*n1+u)
        const int sbase = (u - m + 512) & (N - 1);
        #pragma unroll
        for (int n1 = 0; n1 < 16; ++n1) {
            float2 a = Ysf2[(n1 << 6) + u];
            int s = (sbase + (n1 << 6)) & (N - 1);
            float2 yb = Y2[s];
            xr[n1] = a.x * yb.x - a.y * yb.y;
            xi[n1] = a.x * yb.y + a.y * yb.x;
        }
        dft16(xr, xi);
        #pragma unroll
        for (int r = 1; r < 16; ++r) cmul(xr[r], xi[r], tar[r], tai[r]);

        // wave-local transpose through per-wave LDS buffer (XOR-swizzled)
        asm volatile("s_waitcnt lgkmcnt(0)" ::: "memory");   // WAR vs prev row's reads
        #pragma unroll
        for (int r = 0; r < 16; ++r) {
            int k1 = ((r & 3) << 2) | (r >> 2);
            int el = (k1 << 6) | (((k1u ^ k1) & 15) << 2) | n3;
            tp[el] = make_float2(xr[r], xi[r]);
        }
        asm volatile("s_waitcnt lgkmcnt(0)" ::: "memory");   // RAW write->read
        #pragma unroll
        for (int n2 = 0; n2 < 16; ++n2) {
            int el = (k1u << 6) | (((n2 ^ k1u) & 15) << 2) | n3;
            float2 v = tp[el];
            xr[n2] = v.x; xi[n2] = v.y;
        }

        // phase B: radix-16 over n2 + W_64^{n3*k2}
        dft16(xr, xi);
        #pragma unroll
        for (int r = 1; r < 16; ++r) {
            int k2 = ((r & 3) << 2) | (r >> 2);
            float2 wv = TB2[(k2 << 2) | n3];
            cmul(xr[r], xi[r], wv.x, wv.y);
        }

        // phase C: radix-4 across quad lanes (DPP) + magnitude + reductions
        const float* Mrow  = M + (size_t)m * N + clane;
        const float* Mrow2 = M + (size_t)mm * N + clane;
        const bool domm = (mm != m);
        const float w225 = w * 2.25f;
        float rs = 0.f;
        #pragma unroll
        for (int r = 0; r < 16; ++r) {
            int k2 = ((r & 3) << 2) | (r >> 2);
            float ar = xr[r], ai = xi[r];
            float br = dppf<DPP_XOR2>(ar), bi = dppf<DPP_XOR2>(ai);
            float zr = hi2 ? (br - ar) : (ar + br);
            float zi = hi2 ? (bi - ai) : (ai + bi);
            float qr = dppf<DPP_XOR1>(zr), qi = dppf<DPP_XOR1>(zi);
            float Xr = odd ? (qr - (hi2 ? zi : zr)) : (zr + (hi2 ? qi : qr));
            float Xi = odd ? (qi + (hi2 ? zr : -zi)) : (zi + (hi2 ? -qr : qi));
            float mag2 = Xr * Xr + Xi * Xi;
            float v = 1.5f * sqrtf(mag2);
            rs  += v;
            ttl += w225 * mag2;          // w * v^2
            float ms = Mrow[k2 << 4];
            if (domm) ms += Mrow2[k2 << 4];
            mtl += ms * v;
            colr[r] += w * v;
        }
        rs = wave_sum(rs);
        if (u == 0) {
            ws[OFF_ROWSUM + (size_t)b * N + m] = rs;
            if (mm != m) ws[OFF_ROWSUM + (size_t)b * N + mm] = rs;
        }
    }

    // wave epilogue: reduced MT/TT + column-sum register flush
    mtl = wave_sum(mtl);
    ttl = wave_sum(ttl);
    if (u == 0) {
        atomicAdd(&ws[OFF_SUMMT + b], mtl);
        atomicAdd(&ws[OFF_SUMTT + b], ttl);
    }
    float* colT = ws + OFF_COLT + (size_t)(b * NREP + (cnk & (NREP - 1))) * N;
    #pragma unroll
    for (int r = 0; r < 16; ++r) {
        int k2 = ((r & 3) << 2) | (r >> 2);
        atomicAdd(&colT[clane + (k2 << 4)], colr[r]);
    }
}

__global__ __launch_bounds__(T_) void k_final(float* ws, float* out) {
    __shared__ double redn[4], redd[4];
    const int b = blockIdx.x;
    const int t = threadIdx.x;
    const int wid = t >> 6, lane = t & 63;
    const float* rowsum = ws + OFF_ROWSUM + (size_t)b * N;
    double num = 0.0, den = 0.0;
    #pragma unroll
    for (int q = 0; q < 4; ++q) {
        int j = t + 256 * q;
        double r = (double)rowsum[j];
        float ct = 0.f;
        #pragma unroll
        for (int rep = 0; rep < NREP; ++rep)
            ct += ws[OFF_COLT + (size_t)(b * NREP + rep) * N + j];
        num += (double)ws[OFF_COLSUMM + j] * r;
        den += (double)ct * r;
    }
    #pragma unroll
    for (int o = 32; o > 0; o >>= 1) {
        num += __shfl_down(num, o, 64);
        den += __shfl_down(den, o, 64);
    }
    if (lane == 0) { redn[wid] = num; redd[wid] = den; }
    __syncthreads();
    if (t == 0) {
        double NUM = redn[0] + redn[1] + redn[2] + redn[3];
        double DEN = redd[0] + redd[1] + redd[2] + redd[3];
        double mu = NUM / DEN;
        double r = (double)ws[OFF_SUMM2] - 2.0 * mu * (double)ws[OFF_SUMMT + b]
                 + mu * mu * (double)ws[OFF_SUMTT + b];
        float mx = ws[OFF_MAXM];  // float bits written via uint atomicMax
        double norm = 1048576.0 * (double)mx * (double)mx;
        atomicAdd(out, (float)(sqrt(r / norm) / 8.0));
    }
}

extern "C" void kernel_launch(void* const* d_in, const int* in_sizes, int n_in,
                              void* d_out, int out_size, void* d_ws, size_t ws_size,
                              hipStream_t stream) {
    const float* pred = (const float*)d_in[0];   // [8, 2048]
    const float* M = (const float*)d_in[2];      // [1024, 1024]
    float* ws = (float*)d_ws;
    float* out = (float*)d_out;

    k_prep<<<12, T_, 0, stream>>>(ws, out);
    dim3 grid(CHUNKS, B_ + 1);
    k_row<<<grid, T_, 0, stream>>>(pred, M, ws);
    k_final<<<B_, T_, 0, stream>>>(ws, out);
}